// Round 2
// baseline (831.796 us; speedup 1.0000x reference)
//
#include <hip/hip_runtime.h>
#include <math.h>

typedef _Float16 half8 __attribute__((ext_vector_type(8)));
typedef float f32x4 __attribute__((ext_vector_type(4)));
typedef unsigned int u32;

#define AS1 __attribute__((address_space(1)))
#define AS3 __attribute__((address_space(3)))

__device__ __forceinline__ void g2lds16(const void* g, void* l) {
    __builtin_amdgcn_global_load_lds((const AS1 u32*)g, (AS3 u32*)l, 16, 0, 0);
}

#if __has_builtin(__builtin_amdgcn_exp2f)
#define EXP2F(x) __builtin_amdgcn_exp2f(x)
#else
#define EXP2F(x) exp2f(x)
#endif

// ---------------- fused f32 -> f16 conversion (x + all weights) ----------------
__global__ __launch_bounds__(256)
void cvt_all(const float* __restrict__ x, const float* __restrict__ wq,
             const float* __restrict__ wk, const float* __restrict__ wv,
             const float* __restrict__ wo, const float* __restrict__ w1,
             const float* __restrict__ w2, _Float16* __restrict__ xh,
             _Float16* __restrict__ qkvw, _Float16* __restrict__ woh,
             _Float16* __restrict__ w1h, _Float16* __restrict__ w2h)
{
    const int bid = blockIdx.x;
    const float* src; _Float16* dst; int g;
    if (bid < 8192)      { src = x;  dst = xh;            g = bid*256 + threadIdx.x; }
    else if (bid < 8320) { src = wq; dst = qkvw;          g = (bid-8192)*256 + threadIdx.x; }
    else if (bid < 8448) { src = wk; dst = qkvw + 262144; g = (bid-8320)*256 + threadIdx.x; }
    else if (bid < 8576) { src = wv; dst = qkvw + 524288; g = (bid-8448)*256 + threadIdx.x; }
    else if (bid < 8704) { src = wo; dst = woh;           g = (bid-8576)*256 + threadIdx.x; }
    else if (bid < 9216) { src = w1; dst = w1h;           g = (bid-8704)*256 + threadIdx.x; }
    else                 { src = w2; dst = w2h;           g = (bid-9216)*256 + threadIdx.x; }
    const float4* p = (const float4*)src + (size_t)g * 2;
    float4 a = p[0], b = p[1];
    half8 h;
    h[0]=(_Float16)a.x; h[1]=(_Float16)a.y; h[2]=(_Float16)a.z; h[3]=(_Float16)a.w;
    h[4]=(_Float16)b.x; h[5]=(_Float16)b.y; h[6]=(_Float16)b.z; h[7]=(_Float16)b.w;
    *((half8*)dst + g) = h;
}

__global__ __launch_bounds__(256)
void pack_bias(const float* __restrict__ bq, const float* __restrict__ bk,
               const float* __restrict__ bv, float* __restrict__ o)
{
    const int i = blockIdx.x * 256 + threadIdx.x;   // grid 6
    o[i] = i < 512 ? bq[i] : (i < 1024 ? bk[i-512] : bv[i-1024]);
}

// ---------------- GEMM: C[M,N] = A[M,K] @ B[N,K]^T + bias (+epilogue) -------
// MODE 0: out f16 = acc + bias; Q/K cols -> Cout, V cols (>=1024) -> vT transposed
// MODE 1: out f16 = gelu(acc + bias)    (FF1, sigmoid-form gelu)
// MODE 2: out f32 = acc + bias + resf   (WO + fp32 residual)
// MODE 3: out f32 = acc + bias + resh   (FF2 + f16 residual)
template<int MODE>
__global__ __launch_bounds__(256)
void gemm_bt(const _Float16* __restrict__ A, const _Float16* __restrict__ B,
             const float* __restrict__ bias, const float* __restrict__ resf,
             const _Float16* __restrict__ resh, _Float16* __restrict__ vTout,
             void* __restrict__ Cout, int M, int N, int K)
{
    __shared__ __align__(16) _Float16 As[128 * 32];
    __shared__ __align__(16) _Float16 Bs[128 * 32];
    const int tid = threadIdx.x;
    const int lane = tid & 63;
    const int w = tid >> 6;
    const int wm = w >> 1, wn = w & 1;
    const int m0 = blockIdx.y * 128, n0 = blockIdx.x * 128;
    const int lrow = lane & 15;
    const int lk = (lane >> 4) * 8;

    f32x4 acc[4][4];
#pragma unroll
    for (int i = 0; i < 4; ++i)
#pragma unroll
        for (int j = 0; j < 4; ++j) acc[i][j] = (f32x4)0.0f;

    for (int k0 = 0; k0 < K; k0 += 32) {
#pragma unroll
        for (int i = 0; i < 2; ++i) {
            int gbase = i * 256 + w * 64;           // wave-uniform
            int g = gbase + lane;
            g2lds16(A + (size_t)(m0 + (g >> 2)) * K + k0 + (g & 3) * 8,
                    (char*)As + (size_t)gbase * 16);
            g2lds16(B + (size_t)(n0 + (g >> 2)) * K + k0 + (g & 3) * 8,
                    (char*)Bs + (size_t)gbase * 16);
        }
        __syncthreads();
        half8 af[4], bfr[4];
#pragma unroll
        for (int t = 0; t < 4; ++t) {
            af[t]  = *(const half8*)(As + (wm * 64 + t * 16 + lrow) * 32 + lk);
            bfr[t] = *(const half8*)(Bs + (wn * 64 + t * 16 + lrow) * 32 + lk);
        }
#pragma unroll
        for (int mi = 0; mi < 4; ++mi)
#pragma unroll
            for (int ni = 0; ni < 4; ++ni)
                acc[mi][ni] = __builtin_amdgcn_mfma_f32_16x16x32_f16(af[mi], bfr[ni], acc[mi][ni], 0, 0, 0);
        __syncthreads();
    }

    const int rq = (lane >> 4) * 4;
#pragma unroll
    for (int mi = 0; mi < 4; ++mi) {
#pragma unroll
        for (int ni = 0; ni < 4; ++ni) {
            const int col = n0 + wn * 64 + ni * 16 + lrow;
            const float bv = bias[col];
#pragma unroll
            for (int r = 0; r < 4; ++r) {
                const int row = m0 + wm * 64 + mi * 16 + rq + r;
                const size_t idx = (size_t)row * N + col;
                float v = acc[mi][ni][r] + bv;
                if (MODE == 0) {
                    if (col < 1024) {
                        ((_Float16*)Cout)[idx] = (_Float16)v;
                    } else {
                        // V region -> vT[(bf*8+h)][dk][s]  (64 x 1024 per head)
                        const int dkf = col - 1024;
                        const size_t tidx = (((size_t)((row >> 10) * 8 + (dkf >> 6))) << 16)
                                          + ((size_t)(dkf & 63) << 10) + (size_t)(row & 1023);
                        vTout[tidx] = (_Float16)v;
                    }
                } else if (MODE == 1) {
                    // gelu(v) ~= v * sigmoid(1.5957691*v*(1+0.044715 v^2))
                    float t2 = -1.5957691216057308f * v * fmaf(v * v, 0.044715f, 1.0f);
                    float e = __expf(t2);
                    ((_Float16*)Cout)[idx] = (_Float16)(v * __builtin_amdgcn_rcpf(1.0f + e));
                } else if (MODE == 2) {
                    ((float*)Cout)[idx] = v + resf[idx];
                } else {
                    ((float*)Cout)[idx] = v + (float)resh[idx];
                }
            }
        }
    }
}

// ---------------- flash attention (no-max softmax, 128-query tile) ----------------
// grid: (S/128, BF*H) = (8, 256). block = 4 waves; each wave owns 32 queries.
// QKV layout [32768, 1536]: Q cols 0..511, K cols 512..1023 (V lives in vT).
// vT layout: [bf*8+h][dk=64][s=1024] f16.
//
// v3: - K and V^T fragments loaded DIRECTLY from global (L2-hot, XCD-swizzled)
//       -> zero __syncthreads in the k-loop, no K/V LDS staging
//     - exp2-folded scale (one v_mul less per element)
//     - softmax denominator via ones-MFMA (same C layout as acc)
//     - s_setprio(1) around the PV MFMA cluster
__global__ __launch_bounds__(256, 4)
void attn_fwd(const _Float16* __restrict__ QKV, const _Float16* __restrict__ vT,
              const int* __restrict__ mask, _Float16* __restrict__ ctx)
{
    constexpr int SQ = 72;                           // P row stride (halves)
    __shared__ __align__(16) _Float16 Ps[4][32 * SQ];    // 18432 B
    __shared__ float scs[1024];                          // 4096 B -> 22528 total

    const int tid = threadIdx.x;
    const int lane = tid & 63;
    const int w = tid >> 6;

    // XCD-aware remap: blocks p with equal (p&7) land on the same XCD (round-robin
    // dispatch); give each XCD whole heads so all 8 q-tiles of a head share one L2.
    const int p = blockIdx.y * 8 + blockIdx.x;
    const int ii = p >> 3;
    const int headlin = (p & 7) * 32 + (ii >> 3);
    const int bf = headlin >> 3;
    const int hh = headlin & 7;
    const int q0 = (ii & 7) * 128;

    const int lrow = lane & 15;
    const int lq = lane >> 4;

    // fused per-key scale (softmax scale * eclipse boost) * log2(e), once
    {
        const int* mrow = mask + (bf >> 3) * 1024;   // b = bf / F
        const int i = tid * 4;
        int4 mm = *(const int4*)(mrow + i);
        scs[i + 0] = mm.x ? 0.36067376f : 0.18033688f;
        scs[i + 1] = mm.y ? 0.36067376f : 0.18033688f;
        scs[i + 2] = mm.z ? 0.36067376f : 0.18033688f;
        scs[i + 3] = mm.w ? 0.36067376f : 0.18033688f;
    }
    __syncthreads();                                 // the only barrier
    constexpr float B2 = -7.2134752f;                // -5 * log2(e)

    // Q fragments straight from global (once per block, amortized over 8 tiles)
    half8 qf[2][2];
#pragma unroll
    for (int qi = 0; qi < 2; ++qi) {
        const _Float16* qp = QKV + (size_t)(bf * 1024 + q0 + w * 32 + qi * 16 + lrow) * 1536 + hh * 64 + lq * 8;
        qf[qi][0] = *(const half8*)qp;
        qf[qi][1] = *(const half8*)(qp + 32);
    }

    const _Float16* Kg = QKV + (size_t)bf * 1024 * 1536 + 512 + hh * 64;
    const _Float16* Vg = vT + (size_t)(bf * 8 + hh) * 65536;

    f32x4 acc[2][4];
#pragma unroll
    for (int qi = 0; qi < 2; ++qi)
#pragma unroll
        for (int d = 0; d < 4; ++d) acc[qi][d] = (f32x4)0.0f;
    f32x4 acc_l[2] = {(f32x4)0.0f, (f32x4)0.0f};
    const half8 ones = {(_Float16)1.f,(_Float16)1.f,(_Float16)1.f,(_Float16)1.f,
                        (_Float16)1.f,(_Float16)1.f,(_Float16)1.f,(_Float16)1.f};
    _Float16* Pw = &Ps[w][0];

    for (int kt = 0; kt < 1024; kt += 64) {
        // prefetch V^T fragments for this tile (latency hides under QK + exp)
        half8 vf[4][2];
#pragma unroll
        for (int d = 0; d < 4; ++d)
#pragma unroll
            for (int t = 0; t < 2; ++t)
                vf[d][t] = *(const half8*)(Vg + (size_t)(d * 16 + lrow) * 1024 + kt + t * 32 + lq * 8);

        // QK^T -> p = exp2(s*sc2 + B2) -> per-wave P buffer (f16)
#pragma unroll
        for (int nt = 0; nt < 4; ++nt) {
            const _Float16* kp = Kg + (size_t)(kt + nt * 16 + lrow) * 1536 + lq * 8;
            half8 kf0 = *(const half8*)kp;
            half8 kf1 = *(const half8*)(kp + 32);
            const float sc = scs[kt + nt * 16 + lrow];
#pragma unroll
            for (int qi = 0; qi < 2; ++qi) {
                f32x4 s = (f32x4)0.0f;
                s = __builtin_amdgcn_mfma_f32_16x16x32_f16(qf[qi][0], kf0, s, 0, 0, 0);
                s = __builtin_amdgcn_mfma_f32_16x16x32_f16(qf[qi][1], kf1, s, 0, 0, 0);
#pragma unroll
                for (int r = 0; r < 4; ++r)
                    Pw[(qi * 16 + lq * 4 + r) * SQ + nt * 16 + lrow] =
                        (_Float16)EXP2F(fmaf(s[r], sc, B2));
            }
        }

        // P (C-layout -> A-layout via per-wave LDS), then PV
        half8 pf[2][2];
#pragma unroll
        for (int qi = 0; qi < 2; ++qi) {
            pf[qi][0] = *(const half8*)(Pw + (qi * 16 + lrow) * SQ + lq * 8);
            pf[qi][1] = *(const half8*)(Pw + (qi * 16 + lrow) * SQ + 32 + lq * 8);
        }
        __builtin_amdgcn_s_setprio(1);
#pragma unroll
        for (int d = 0; d < 4; ++d)
#pragma unroll
            for (int qi = 0; qi < 2; ++qi) {
                acc[qi][d] = __builtin_amdgcn_mfma_f32_16x16x32_f16(pf[qi][0], vf[d][0], acc[qi][d], 0, 0, 0);
                acc[qi][d] = __builtin_amdgcn_mfma_f32_16x16x32_f16(pf[qi][1], vf[d][1], acc[qi][d], 0, 0, 0);
            }
        // softmax denominator: row-sum of P via ones-MFMA (same C layout as acc)
#pragma unroll
        for (int qi = 0; qi < 2; ++qi) {
            acc_l[qi] = __builtin_amdgcn_mfma_f32_16x16x32_f16(pf[qi][0], ones, acc_l[qi], 0, 0, 0);
            acc_l[qi] = __builtin_amdgcn_mfma_f32_16x16x32_f16(pf[qi][1], ones, acc_l[qi], 0, 0, 0);
        }
        __builtin_amdgcn_s_setprio(0);
    }

#pragma unroll
    for (int qi = 0; qi < 2; ++qi) {
#pragma unroll
        for (int r = 0; r < 4; ++r) {
            const float inv = 1.0f / acc_l[qi][r];
            const int row = q0 + w * 32 + qi * 16 + lq * 4 + r;
            _Float16* cp = ctx + ((size_t)bf * 1024 + row) * 512 + hh * 64;
#pragma unroll
            for (int d = 0; d < 4; ++d)
                cp[d * 16 + lrow] = (_Float16)(acc[qi][d][r] * inv);
        }
    }
}

// ---------------- LayerNorm over D=512, 1 wave per row ----------------
template<int OUTH>
__global__ __launch_bounds__(256)
void ln_fused(const float* __restrict__ X, const float* __restrict__ gma,
              const float* __restrict__ bta, float* __restrict__ outF,
              _Float16* __restrict__ outH)
{
    const int row = blockIdx.x * 4 + (threadIdx.x >> 6);
    const int lane = threadIdx.x & 63;
    const float4* xr = (const float4*)(X + (size_t)row * 512);
    float4 a = xr[lane * 2], c = xr[lane * 2 + 1];
    float s  = a.x + a.y + a.z + a.w + c.x + c.y + c.z + c.w;
    float s2 = a.x * a.x + a.y * a.y + a.z * a.z + a.w * a.w
             + c.x * c.x + c.y * c.y + c.z * c.z + c.w * c.w;
#pragma unroll
    for (int m = 1; m < 64; m <<= 1) { s += __shfl_xor(s, m); s2 += __shfl_xor(s2, m); }
    const float mean = s * (1.0f / 512.0f);
    const float inv = rsqrtf(s2 * (1.0f / 512.0f) - mean * mean + 1e-5f);
    const float4* gp = (const float4*)gma;
    const float4* bp = (const float4*)bta;
    float4 g0 = gp[lane * 2], g1 = gp[lane * 2 + 1];
    float4 b0 = bp[lane * 2], b1 = bp[lane * 2 + 1];
    float4 o0, o1;
    o0.x = (a.x - mean) * inv * g0.x + b0.x; o0.y = (a.y - mean) * inv * g0.y + b0.y;
    o0.z = (a.z - mean) * inv * g0.z + b0.z; o0.w = (a.w - mean) * inv * g0.w + b0.w;
    o1.x = (c.x - mean) * inv * g1.x + b1.x; o1.y = (c.y - mean) * inv * g1.y + b1.y;
    o1.z = (c.z - mean) * inv * g1.z + b1.z; o1.w = (c.w - mean) * inv * g1.w + b1.w;
    if (OUTH) {
        half8 hv;
        hv[0] = (_Float16)o0.x; hv[1] = (_Float16)o0.y; hv[2] = (_Float16)o0.z; hv[3] = (_Float16)o0.w;
        hv[4] = (_Float16)o1.x; hv[5] = (_Float16)o1.y; hv[6] = (_Float16)o1.z; hv[7] = (_Float16)o1.w;
        *((half8*)(outH + (size_t)row * 512) + lane) = hv;
    } else {
        float4* op = (float4*)(outF + (size_t)row * 512);
        op[lane * 2] = o0; op[lane * 2 + 1] = o1;
    }
}

extern "C" void kernel_launch(void* const* d_in, const int* in_sizes, int n_in,
                              void* d_out, int out_size, void* d_ws, size_t ws_size,
                              hipStream_t stream)
{
    const float* x   = (const float*)d_in[0];
    const int* mask  = (const int*)d_in[1];
    const float* wq  = (const float*)d_in[2];  const float* bq  = (const float*)d_in[3];
    const float* wk  = (const float*)d_in[4];  const float* bk  = (const float*)d_in[5];
    const float* wv  = (const float*)d_in[6];  const float* bv  = (const float*)d_in[7];
    const float* wo  = (const float*)d_in[8];  const float* bo  = (const float*)d_in[9];
    const float* w1  = (const float*)d_in[10]; const float* b1  = (const float*)d_in[11];
    const float* w2  = (const float*)d_in[12]; const float* b2  = (const float*)d_in[13];
    const float* g1  = (const float*)d_in[14]; const float* be1 = (const float*)d_in[15];
    const float* g2  = (const float*)d_in[16]; const float* be2 = (const float*)d_in[17];
    float* out = (float*)d_out;

    char* ws = (char*)d_ws;
    _Float16* qkvh = (_Float16*)(ws);                 // [32768,1536] (V region unused)
    _Float16* ctxh = (_Float16*)(ws + 100663296);
    _Float16* gh   = (_Float16*)(ws);
    _Float16* xh   = (_Float16*)(ws + 134217728);
    float*    res  = (float*)   (ws + 134217728);
    _Float16* vTh  = (_Float16*)(ws + 167772160);     // [256][64][1024] f16, dead before res upper half is written
    _Float16* hhb  = (_Float16*)(ws + 201326592);
    float*    biasf= (float*)   (ws + 201326592);
    _Float16* qkvw = (_Float16*)(ws + 234881024);
    _Float16* woh  = (_Float16*)(ws + 236453888);
    _Float16* w1h  = (_Float16*)(ws + 236978176);
    _Float16* w2h  = (_Float16*)(ws + 239075328);

    dim3 blk(256);

    cvt_all<<<9728, blk, 0, stream>>>(x, wq, wk, wv, wo, w1, w2, xh, qkvw, woh, w1h, w2h);
    pack_bias<<<6, blk, 0, stream>>>(bq, bk, bv, biasf);

    // fused QKV: [32768,512] @ [1536,512]^T -> Q/K into qkvh, V transposed into vTh
    gemm_bt<0><<<dim3(12, 256), blk, 0, stream>>>(xh, qkvw, biasf, nullptr, nullptr, vTh, qkvh, 32768, 1536, 512);

    // flash attention with eclipse boost (128-query tiles, barrier-free k-loop)
    attn_fwd<<<dim3(8, 256), blk, 0, stream>>>(qkvh, vTh, mask, ctxh);

    // WO projection + bias + fp32 residual (original x, raw reshape)
    gemm_bt<2><<<dim3(4, 256), blk, 0, stream>>>(ctxh, woh, bo, x, nullptr, nullptr, res, 32768, 512, 512);

    // LN1 -> h (f16)
    ln_fused<1><<<8192, blk, 0, stream>>>(res, g1, be1, nullptr, hhb);

    // FF1 + gelu: [32768,512] @ [2048,512]^T
    gemm_bt<1><<<dim3(16, 256), blk, 0, stream>>>(hhb, w1h, b1, nullptr, nullptr, nullptr, gh, 32768, 2048, 512);

    // FF2 + bias + residual(h): [32768,2048] @ [512,2048]^T
    gemm_bt<3><<<dim3(4, 256), blk, 0, stream>>>(gh, w2h, b2, nullptr, hhb, nullptr, res, 32768, 512, 2048);

    // LN2 -> out (f32)
    ln_fused<0><<<8192, blk, 0, stream>>>(res, g2, be2, out, nullptr);
}

// Round 3
// 742.569 us; speedup vs baseline: 1.1202x; 1.1202x over previous
//
#include <hip/hip_runtime.h>
#include <math.h>

typedef _Float16 half8 __attribute__((ext_vector_type(8)));
typedef float f32x4 __attribute__((ext_vector_type(4)));
typedef unsigned int u32;

#define AS1 __attribute__((address_space(1)))
#define AS3 __attribute__((address_space(3)))

__device__ __forceinline__ void g2lds16(const void* g, void* l) {
    __builtin_amdgcn_global_load_lds((const AS1 u32*)g, (AS3 u32*)l, 16, 0, 0);
}

#if __has_builtin(__builtin_amdgcn_exp2f)
#define EXP2F(x) __builtin_amdgcn_exp2f(x)
#else
#define EXP2F(x) exp2f(x)
#endif

// ---------------- fused f32 -> f16 conversion (x + all weights) ----------------
__global__ __launch_bounds__(256)
void cvt_all(const float* __restrict__ x, const float* __restrict__ wq,
             const float* __restrict__ wk, const float* __restrict__ wv,
             const float* __restrict__ wo, const float* __restrict__ w1,
             const float* __restrict__ w2, _Float16* __restrict__ xh,
             _Float16* __restrict__ qkvw, _Float16* __restrict__ woh,
             _Float16* __restrict__ w1h, _Float16* __restrict__ w2h)
{
    const int bid = blockIdx.x;
    const float* src; _Float16* dst; int g;
    if (bid < 8192)      { src = x;  dst = xh;            g = bid*256 + threadIdx.x; }
    else if (bid < 8320) { src = wq; dst = qkvw;          g = (bid-8192)*256 + threadIdx.x; }
    else if (bid < 8448) { src = wk; dst = qkvw + 262144; g = (bid-8320)*256 + threadIdx.x; }
    else if (bid < 8576) { src = wv; dst = qkvw + 524288; g = (bid-8448)*256 + threadIdx.x; }
    else if (bid < 8704) { src = wo; dst = woh;           g = (bid-8576)*256 + threadIdx.x; }
    else if (bid < 9216) { src = w1; dst = w1h;           g = (bid-8704)*256 + threadIdx.x; }
    else                 { src = w2; dst = w2h;           g = (bid-9216)*256 + threadIdx.x; }
    const float4* p = (const float4*)src + (size_t)g * 2;
    float4 a = p[0], b = p[1];
    half8 h;
    h[0]=(_Float16)a.x; h[1]=(_Float16)a.y; h[2]=(_Float16)a.z; h[3]=(_Float16)a.w;
    h[4]=(_Float16)b.x; h[5]=(_Float16)b.y; h[6]=(_Float16)b.z; h[7]=(_Float16)b.w;
    *((half8*)dst + g) = h;
}

__global__ __launch_bounds__(256)
void pack_bias(const float* __restrict__ bq, const float* __restrict__ bk,
               const float* __restrict__ bv, float* __restrict__ o)
{
    const int i = blockIdx.x * 256 + threadIdx.x;   // grid 6
    o[i] = i < 512 ? bq[i] : (i < 1024 ? bk[i-512] : bv[i-1024]);
}

// ---------------- GEMM: C[M,N] = A[M,K] @ B[N,K]^T + bias (+epilogue) -------
// MODE 0: out f16 = acc + bias; Q/K cols -> Cout, V cols (>=1024) -> vT transposed
// MODE 1: out f16 = gelu(acc + bias)    (FF1, sigmoid-form gelu)
// MODE 2: out f32 = acc + bias + resf   (WO + fp32 residual)
// MODE 3: out f32 = acc + bias + resh   (FF2 + f16 residual)
template<int MODE>
__global__ __launch_bounds__(256)
void gemm_bt(const _Float16* __restrict__ A, const _Float16* __restrict__ B,
             const float* __restrict__ bias, const float* __restrict__ resf,
             const _Float16* __restrict__ resh, _Float16* __restrict__ vTout,
             void* __restrict__ Cout, int M, int N, int K)
{
    __shared__ __align__(16) _Float16 As[128 * 32];
    __shared__ __align__(16) _Float16 Bs[128 * 32];
    const int tid = threadIdx.x;
    const int lane = tid & 63;
    const int w = tid >> 6;
    const int wm = w >> 1, wn = w & 1;
    const int m0 = blockIdx.y * 128, n0 = blockIdx.x * 128;
    const int lrow = lane & 15;
    const int lk = (lane >> 4) * 8;

    f32x4 acc[4][4];
#pragma unroll
    for (int i = 0; i < 4; ++i)
#pragma unroll
        for (int j = 0; j < 4; ++j) acc[i][j] = (f32x4)0.0f;

    for (int k0 = 0; k0 < K; k0 += 32) {
#pragma unroll
        for (int i = 0; i < 2; ++i) {
            int gbase = i * 256 + w * 64;           // wave-uniform
            int g = gbase + lane;
            g2lds16(A + (size_t)(m0 + (g >> 2)) * K + k0 + (g & 3) * 8,
                    (char*)As + (size_t)gbase * 16);
            g2lds16(B + (size_t)(n0 + (g >> 2)) * K + k0 + (g & 3) * 8,
                    (char*)Bs + (size_t)gbase * 16);
        }
        __syncthreads();
        half8 af[4], bfr[4];
#pragma unroll
        for (int t = 0; t < 4; ++t) {
            af[t]  = *(const half8*)(As + (wm * 64 + t * 16 + lrow) * 32 + lk);
            bfr[t] = *(const half8*)(Bs + (wn * 64 + t * 16 + lrow) * 32 + lk);
        }
#pragma unroll
        for (int mi = 0; mi < 4; ++mi)
#pragma unroll
            for (int ni = 0; ni < 4; ++ni)
                acc[mi][ni] = __builtin_amdgcn_mfma_f32_16x16x32_f16(af[mi], bfr[ni], acc[mi][ni], 0, 0, 0);
        __syncthreads();
    }

    const int rq = (lane >> 4) * 4;
#pragma unroll
    for (int mi = 0; mi < 4; ++mi) {
#pragma unroll
        for (int ni = 0; ni < 4; ++ni) {
            const int col = n0 + wn * 64 + ni * 16 + lrow;
            const float bv = bias[col];
#pragma unroll
            for (int r = 0; r < 4; ++r) {
                const int row = m0 + wm * 64 + mi * 16 + rq + r;
                const size_t idx = (size_t)row * N + col;
                float v = acc[mi][ni][r] + bv;
                if (MODE == 0) {
                    if (col < 1024) {
                        ((_Float16*)Cout)[idx] = (_Float16)v;
                    } else {
                        // V region -> vT[(bf*8+h)][dk][s]  (64 x 1024 per head)
                        const int dkf = col - 1024;
                        const size_t tidx = (((size_t)((row >> 10) * 8 + (dkf >> 6))) << 16)
                                          + ((size_t)(dkf & 63) << 10) + (size_t)(row & 1023);
                        vTout[tidx] = (_Float16)v;
                    }
                } else if (MODE == 1) {
                    // gelu(v) ~= v * sigmoid(1.5957691*v*(1+0.044715 v^2))
                    float t2 = -1.5957691216057308f * v * fmaf(v * v, 0.044715f, 1.0f);
                    float e = __expf(t2);
                    ((_Float16*)Cout)[idx] = (_Float16)(v * __builtin_amdgcn_rcpf(1.0f + e));
                } else if (MODE == 2) {
                    ((float*)Cout)[idx] = v + resf[idx];
                } else {
                    ((float*)Cout)[idx] = v + (float)resh[idx];
                }
            }
        }
    }
}

// ---------------- flash attention (no-max softmax, 128-query tile) ----------------
// grid: (S/128, BF*H) = (8, 256). block = 4 waves; each wave owns 32 queries.
// QKV layout [32768, 1536]: Q cols 0..511, K cols 512..1023 (V lives in vT).
// vT layout: [bf*8+h][dk=64][s=1024] f16.
//
// v4 = v1's verified LDS-staged structure +
//     - V staged coalesced from precomputed vT (no scalar transpose writes)
//     - exp2-folded scale, ones-MFMA softmax denominator
//     - XCD head-affine remap, setprio around PV MFMAs
//     - P/K/V stride 72 -> 68 (P-writes: lq groups at {0,32,64,96}B mod 128
//       = exact 2 lanes/bank, vs v1's {0,64,0,64} 4-way conflict)
__global__ __launch_bounds__(256, 4)
void attn_fwd(const _Float16* __restrict__ QKV, const _Float16* __restrict__ vT,
              const int* __restrict__ mask, _Float16* __restrict__ ctx)
{
    constexpr int SQ = 68;                           // padded row stride (halves)
    __shared__ __align__(16) _Float16 Ks[64 * SQ];       // 8704 B
    __shared__ __align__(16) _Float16 Vts[64 * SQ];      // 8704 B
    __shared__ __align__(16) _Float16 Ps[4][32 * SQ];    // 17408 B
    __shared__ float scs[1024];                          // 4096 B -> 38912 total

    const int tid = threadIdx.x;
    const int lane = tid & 63;
    const int w = tid >> 6;

    // XCD-aware remap: blocks p with equal (p&7) land on the same XCD (round-robin
    // dispatch); give each XCD whole heads so all 8 q-tiles of a head share one L2.
    const int p = blockIdx.y * 8 + blockIdx.x;
    const int ii = p >> 3;
    const int headlin = (p & 7) * 32 + (ii >> 3);
    const int bf = headlin >> 3;
    const int hh = headlin & 7;
    const int q0 = (ii & 7) * 128;

    const int lrow = lane & 15;
    const int lq = lane >> 4;

    // fused per-key scale (softmax scale * eclipse boost) * log2(e), once
    {
        const int* mrow = mask + (bf >> 3) * 1024;   // b = bf / F
        const int i = tid * 4;
        int4 mm = *(const int4*)(mrow + i);
        scs[i + 0] = mm.x ? 0.36067376f : 0.18033688f;
        scs[i + 1] = mm.y ? 0.36067376f : 0.18033688f;
        scs[i + 2] = mm.z ? 0.36067376f : 0.18033688f;
        scs[i + 3] = mm.w ? 0.36067376f : 0.18033688f;
    }
    constexpr float B2 = -7.2134752f;                // -5 * log2(e)

    // Q fragments straight from global (once per block, amortized over 8 tiles)
    half8 qf[2][2];
#pragma unroll
    for (int qi = 0; qi < 2; ++qi) {
        const _Float16* qp = QKV + (size_t)(bf * 1024 + q0 + w * 32 + qi * 16 + lrow) * 1536 + hh * 64 + lq * 8;
        qf[qi][0] = *(const half8*)qp;
        qf[qi][1] = *(const half8*)(qp + 32);
    }

    const _Float16* Kg = QKV + (size_t)bf * 1024 * 1536 + 512 + hh * 64;
    const _Float16* Vg = vT + (size_t)(bf * 8 + hh) * 65536;

    f32x4 acc[2][4];
#pragma unroll
    for (int qi = 0; qi < 2; ++qi)
#pragma unroll
        for (int d = 0; d < 4; ++d) acc[qi][d] = (f32x4)0.0f;
    f32x4 acc_l[2] = {(f32x4)0.0f, (f32x4)0.0f};
    const half8 ones = {(_Float16)1.f,(_Float16)1.f,(_Float16)1.f,(_Float16)1.f,
                        (_Float16)1.f,(_Float16)1.f,(_Float16)1.f,(_Float16)1.f};
    _Float16* Pw = &Ps[w][0];

    for (int kt = 0; kt < 1024; kt += 64) {
        __syncthreads();
        {
            // stage K tile [64 keys x 64 d] and V^T tile [64 d x 64 keys], coalesced
            const int r = tid >> 3, c = (tid & 7) * 8;
            *(uint4*)&Ks[r * SQ + c]         = *(const uint4*)(Kg + (size_t)(kt + r) * 1536 + c);
            *(uint4*)&Ks[(r + 32) * SQ + c]  = *(const uint4*)(Kg + (size_t)(kt + r + 32) * 1536 + c);
            *(uint4*)&Vts[r * SQ + c]        = *(const uint4*)(Vg + (size_t)r * 1024 + kt + c);
            *(uint4*)&Vts[(r + 32) * SQ + c] = *(const uint4*)(Vg + (size_t)(r + 32) * 1024 + kt + c);
        }
        __syncthreads();

        // QK^T -> p = exp2(s*sc2 + B2), no max tracking (|s| bounded << 88)
#pragma unroll
        for (int nt = 0; nt < 4; ++nt) {
            half8 kf0 = *(const half8*)(Ks + (nt * 16 + lrow) * SQ + lq * 8);
            half8 kf1 = *(const half8*)(Ks + (nt * 16 + lrow) * SQ + 32 + lq * 8);
            const float sc = scs[kt + nt * 16 + lrow];
#pragma unroll
            for (int qi = 0; qi < 2; ++qi) {
                f32x4 s = (f32x4)0.0f;
                s = __builtin_amdgcn_mfma_f32_16x16x32_f16(qf[qi][0], kf0, s, 0, 0, 0);
                s = __builtin_amdgcn_mfma_f32_16x16x32_f16(qf[qi][1], kf1, s, 0, 0, 0);
#pragma unroll
                for (int r = 0; r < 4; ++r)
                    Pw[(qi * 16 + lq * 4 + r) * SQ + nt * 16 + lrow] =
                        (_Float16)EXP2F(fmaf(s[r], sc, B2));
            }
        }

        // P (C-layout -> A-layout via per-wave LDS), then PV
        half8 pf[2][2];
#pragma unroll
        for (int qi = 0; qi < 2; ++qi) {
            pf[qi][0] = *(const half8*)(Pw + (qi * 16 + lrow) * SQ + lq * 8);
            pf[qi][1] = *(const half8*)(Pw + (qi * 16 + lrow) * SQ + 32 + lq * 8);
        }
        half8 vf[4][2];
#pragma unroll
        for (int d = 0; d < 4; ++d) {
            vf[d][0] = *(const half8*)(Vts + (d * 16 + lrow) * SQ + lq * 8);
            vf[d][1] = *(const half8*)(Vts + (d * 16 + lrow) * SQ + 32 + lq * 8);
        }
        __builtin_amdgcn_s_setprio(1);
#pragma unroll
        for (int d = 0; d < 4; ++d)
#pragma unroll
            for (int qi = 0; qi < 2; ++qi) {
                acc[qi][d] = __builtin_amdgcn_mfma_f32_16x16x32_f16(pf[qi][0], vf[d][0], acc[qi][d], 0, 0, 0);
                acc[qi][d] = __builtin_amdgcn_mfma_f32_16x16x32_f16(pf[qi][1], vf[d][1], acc[qi][d], 0, 0, 0);
            }
        // softmax denominator: row-sum of P via ones-MFMA (same C layout as acc)
#pragma unroll
        for (int qi = 0; qi < 2; ++qi) {
            acc_l[qi] = __builtin_amdgcn_mfma_f32_16x16x32_f16(pf[qi][0], ones, acc_l[qi], 0, 0, 0);
            acc_l[qi] = __builtin_amdgcn_mfma_f32_16x16x32_f16(pf[qi][1], ones, acc_l[qi], 0, 0, 0);
        }
        __builtin_amdgcn_s_setprio(0);
    }

#pragma unroll
    for (int qi = 0; qi < 2; ++qi) {
#pragma unroll
        for (int r = 0; r < 4; ++r) {
            const float inv = 1.0f / acc_l[qi][r];
            const int row = q0 + w * 32 + qi * 16 + lq * 4 + r;
            _Float16* cp = ctx + ((size_t)bf * 1024 + row) * 512 + hh * 64;
#pragma unroll
            for (int d = 0; d < 4; ++d)
                cp[d * 16 + lrow] = (_Float16)(acc[qi][d][r] * inv);
        }
    }
}

// ---------------- LayerNorm over D=512, 1 wave per row ----------------
template<int OUTH>
__global__ __launch_bounds__(256)
void ln_fused(const float* __restrict__ X, const float* __restrict__ gma,
              const float* __restrict__ bta, float* __restrict__ outF,
              _Float16* __restrict__ outH)
{
    const int row = blockIdx.x * 4 + (threadIdx.x >> 6);
    const int lane = threadIdx.x & 63;
    const float4* xr = (const float4*)(X + (size_t)row * 512);
    float4 a = xr[lane * 2], c = xr[lane * 2 + 1];
    float s  = a.x + a.y + a.z + a.w + c.x + c.y + c.z + c.w;
    float s2 = a.x * a.x + a.y * a.y + a.z * a.z + a.w * a.w
             + c.x * c.x + c.y * c.y + c.z * c.z + c.w * c.w;
#pragma unroll
    for (int m = 1; m < 64; m <<= 1) { s += __shfl_xor(s, m); s2 += __shfl_xor(s2, m); }
    const float mean = s * (1.0f / 512.0f);
    const float inv = rsqrtf(s2 * (1.0f / 512.0f) - mean * mean + 1e-5f);
    const float4* gp = (const float4*)gma;
    const float4* bp = (const float4*)bta;
    float4 g0 = gp[lane * 2], g1 = gp[lane * 2 + 1];
    float4 b0 = bp[lane * 2], b1 = bp[lane * 2 + 1];
    float4 o0, o1;
    o0.x = (a.x - mean) * inv * g0.x + b0.x; o0.y = (a.y - mean) * inv * g0.y + b0.y;
    o0.z = (a.z - mean) * inv * g0.z + b0.z; o0.w = (a.w - mean) * inv * g0.w + b0.w;
    o1.x = (c.x - mean) * inv * g1.x + b1.x; o1.y = (c.y - mean) * inv * g1.y + b1.y;
    o1.z = (c.z - mean) * inv * g1.z + b1.z; o1.w = (c.w - mean) * inv * g1.w + b1.w;
    if (OUTH) {
        half8 hv;
        hv[0] = (_Float16)o0.x; hv[1] = (_Float16)o0.y; hv[2] = (_Float16)o0.z; hv[3] = (_Float16)o0.w;
        hv[4] = (_Float16)o1.x; hv[5] = (_Float16)o1.y; hv[6] = (_Float16)o1.z; hv[7] = (_Float16)o1.w;
        *((half8*)(outH + (size_t)row * 512) + lane) = hv;
    } else {
        float4* op = (float4*)(outF + (size_t)row * 512);
        op[lane * 2] = o0; op[lane * 2 + 1] = o1;
    }
}

extern "C" void kernel_launch(void* const* d_in, const int* in_sizes, int n_in,
                              void* d_out, int out_size, void* d_ws, size_t ws_size,
                              hipStream_t stream)
{
    const float* x   = (const float*)d_in[0];
    const int* mask  = (const int*)d_in[1];
    const float* wq  = (const float*)d_in[2];  const float* bq  = (const float*)d_in[3];
    const float* wk  = (const float*)d_in[4];  const float* bk  = (const float*)d_in[5];
    const float* wv  = (const float*)d_in[6];  const float* bv  = (const float*)d_in[7];
    const float* wo  = (const float*)d_in[8];  const float* bo  = (const float*)d_in[9];
    const float* w1  = (const float*)d_in[10]; const float* b1  = (const float*)d_in[11];
    const float* w2  = (const float*)d_in[12]; const float* b2  = (const float*)d_in[13];
    const float* g1  = (const float*)d_in[14]; const float* be1 = (const float*)d_in[15];
    const float* g2  = (const float*)d_in[16]; const float* be2 = (const float*)d_in[17];
    float* out = (float*)d_out;

    char* ws = (char*)d_ws;
    _Float16* qkvh = (_Float16*)(ws);                 // [32768,1536] (V region unused)
    _Float16* ctxh = (_Float16*)(ws + 100663296);
    _Float16* gh   = (_Float16*)(ws);
    _Float16* xh   = (_Float16*)(ws + 134217728);
    float*    res  = (float*)   (ws + 134217728);
    _Float16* vTh  = (_Float16*)(ws + 167772160);     // [256][64][1024] f16
    _Float16* hhb  = (_Float16*)(ws + 201326592);
    float*    biasf= (float*)   (ws + 201326592);
    _Float16* qkvw = (_Float16*)(ws + 234881024);
    _Float16* woh  = (_Float16*)(ws + 236453888);
    _Float16* w1h  = (_Float16*)(ws + 236978176);
    _Float16* w2h  = (_Float16*)(ws + 239075328);

    dim3 blk(256);

    cvt_all<<<9728, blk, 0, stream>>>(x, wq, wk, wv, wo, w1, w2, xh, qkvw, woh, w1h, w2h);
    pack_bias<<<6, blk, 0, stream>>>(bq, bk, bv, biasf);

    // fused QKV: [32768,512] @ [1536,512]^T -> Q/K into qkvh, V transposed into vTh
    gemm_bt<0><<<dim3(12, 256), blk, 0, stream>>>(xh, qkvw, biasf, nullptr, nullptr, vTh, qkvh, 32768, 1536, 512);

    // flash attention with eclipse boost (128-query tiles, LDS-staged K/V^T)
    attn_fwd<<<dim3(8, 256), blk, 0, stream>>>(qkvh, vTh, mask, ctxh);

    // WO projection + bias + fp32 residual (original x, raw reshape)
    gemm_bt<2><<<dim3(4, 256), blk, 0, stream>>>(ctxh, woh, bo, x, nullptr, nullptr, res, 32768, 512, 512);

    // LN1 -> h (f16)
    ln_fused<1><<<8192, blk, 0, stream>>>(res, g1, be1, nullptr, hhb);

    // FF1 + gelu: [32768,512] @ [2048,512]^T
    gemm_bt<1><<<dim3(16, 256), blk, 0, stream>>>(hhb, w1h, b1, nullptr, nullptr, nullptr, gh, 32768, 2048, 512);

    // FF2 + bias + residual(h): [32768,2048] @ [512,2048]^T
    gemm_bt<3><<<dim3(4, 256), blk, 0, stream>>>(gh, w2h, b2, nullptr, hhb, nullptr, res, 32768, 512, 2048);

    // LN2 -> out (f32)
    ln_fused<0><<<8192, blk, 0, stream>>>(res, g2, be2, out, nullptr);
}

// Round 4
// 735.371 us; speedup vs baseline: 1.1311x; 1.0098x over previous
//
#include <hip/hip_runtime.h>
#include <math.h>

typedef _Float16 half8 __attribute__((ext_vector_type(8)));
typedef float f32x4 __attribute__((ext_vector_type(4)));
typedef unsigned int u32;

#define AS1 __attribute__((address_space(1)))
#define AS3 __attribute__((address_space(3)))

__device__ __forceinline__ void g2lds16(const void* g, void* l) {
    __builtin_amdgcn_global_load_lds((const AS1 u32*)g, (AS3 u32*)l, 16, 0, 0);
}

#if __has_builtin(__builtin_amdgcn_exp2f)
#define EXP2F(x) __builtin_amdgcn_exp2f(x)
#else
#define EXP2F(x) exp2f(x)
#endif

// ---------------- fused f32 -> f16 conversion (x + all weights) ----------------
__global__ __launch_bounds__(256)
void cvt_all(const float* __restrict__ x, const float* __restrict__ wq,
             const float* __restrict__ wk, const float* __restrict__ wv,
             const float* __restrict__ wo, const float* __restrict__ w1,
             const float* __restrict__ w2, _Float16* __restrict__ xh,
             _Float16* __restrict__ qkvw, _Float16* __restrict__ woh,
             _Float16* __restrict__ w1h, _Float16* __restrict__ w2h)
{
    const int bid = blockIdx.x;
    const float* src; _Float16* dst; int g;
    if (bid < 8192)      { src = x;  dst = xh;            g = bid*256 + threadIdx.x; }
    else if (bid < 8320) { src = wq; dst = qkvw;          g = (bid-8192)*256 + threadIdx.x; }
    else if (bid < 8448) { src = wk; dst = qkvw + 262144; g = (bid-8320)*256 + threadIdx.x; }
    else if (bid < 8576) { src = wv; dst = qkvw + 524288; g = (bid-8448)*256 + threadIdx.x; }
    else if (bid < 8704) { src = wo; dst = woh;           g = (bid-8576)*256 + threadIdx.x; }
    else if (bid < 9216) { src = w1; dst = w1h;           g = (bid-8704)*256 + threadIdx.x; }
    else                 { src = w2; dst = w2h;           g = (bid-9216)*256 + threadIdx.x; }
    const float4* p = (const float4*)src + (size_t)g * 2;
    float4 a = p[0], b = p[1];
    half8 h;
    h[0]=(_Float16)a.x; h[1]=(_Float16)a.y; h[2]=(_Float16)a.z; h[3]=(_Float16)a.w;
    h[4]=(_Float16)b.x; h[5]=(_Float16)b.y; h[6]=(_Float16)b.z; h[7]=(_Float16)b.w;
    *((half8*)dst + g) = h;
}

__global__ __launch_bounds__(256)
void pack_bias(const float* __restrict__ bq, const float* __restrict__ bk,
               const float* __restrict__ bv, float* __restrict__ o)
{
    const int i = blockIdx.x * 256 + threadIdx.x;   // grid 6
    o[i] = i < 512 ? bq[i] : (i < 1024 ? bk[i-512] : bv[i-1024]);
}

// ---------------- GEMM: C[M,N] = A[M,K] @ B[N,K]^T + bias (+epilogue) -------
// MODE 0: out f16 = acc + bias; Q/K cols -> Cout, V cols (>=1024) -> vT transposed
// MODE 1: out f16 = gelu(acc + bias)    (FF1, sigmoid-form gelu)
// MODE 2: out f32 = acc + bias + resf   (WO + fp32 residual)
// MODE 3: out f32 = acc + bias + resh   (FF2 + f16 residual)
// v5: XCD-chunked block swizzle — each XCD owns a contiguous M-panel chunk so
//     A-panels are re-read from ONE XCD's L2 instead of all eight.
template<int MODE>
__global__ __launch_bounds__(256)
void gemm_bt(const _Float16* __restrict__ A, const _Float16* __restrict__ B,
             const float* __restrict__ bias, const float* __restrict__ resf,
             const _Float16* __restrict__ resh, _Float16* __restrict__ vTout,
             void* __restrict__ Cout, int M, int N, int K)
{
    __shared__ __align__(16) _Float16 As[128 * 32];
    __shared__ __align__(16) _Float16 Bs[128 * 32];
    const int tid = threadIdx.x;
    const int lane = tid & 63;
    const int w = tid >> 6;
    const int wm = w >> 1, wn = w & 1;

    // bijective XCD swizzle (nwg % 8 == 0 for all our launches)
    const int gx = gridDim.x;
    const int nwg = gx * gridDim.y;
    int bid = blockIdx.y * gx + blockIdx.x;
    bid = (bid & 7) * (nwg >> 3) + (bid >> 3);
    const int m0 = (bid / gx) * 128, n0 = (bid % gx) * 128;

    const int lrow = lane & 15;
    const int lk = (lane >> 4) * 8;

    f32x4 acc[4][4];
#pragma unroll
    for (int i = 0; i < 4; ++i)
#pragma unroll
        for (int j = 0; j < 4; ++j) acc[i][j] = (f32x4)0.0f;

    for (int k0 = 0; k0 < K; k0 += 32) {
#pragma unroll
        for (int i = 0; i < 2; ++i) {
            int gbase = i * 256 + w * 64;           // wave-uniform
            int g = gbase + lane;
            g2lds16(A + (size_t)(m0 + (g >> 2)) * K + k0 + (g & 3) * 8,
                    (char*)As + (size_t)gbase * 16);
            g2lds16(B + (size_t)(n0 + (g >> 2)) * K + k0 + (g & 3) * 8,
                    (char*)Bs + (size_t)gbase * 16);
        }
        __syncthreads();
        half8 af[4], bfr[4];
#pragma unroll
        for (int t = 0; t < 4; ++t) {
            af[t]  = *(const half8*)(As + (wm * 64 + t * 16 + lrow) * 32 + lk);
            bfr[t] = *(const half8*)(Bs + (wn * 64 + t * 16 + lrow) * 32 + lk);
        }
#pragma unroll
        for (int mi = 0; mi < 4; ++mi)
#pragma unroll
            for (int ni = 0; ni < 4; ++ni)
                acc[mi][ni] = __builtin_amdgcn_mfma_f32_16x16x32_f16(af[mi], bfr[ni], acc[mi][ni], 0, 0, 0);
        __syncthreads();
    }

    const int rq = (lane >> 4) * 4;
#pragma unroll
    for (int mi = 0; mi < 4; ++mi) {
#pragma unroll
        for (int ni = 0; ni < 4; ++ni) {
            const int col = n0 + wn * 64 + ni * 16 + lrow;
            const float bv = bias[col];
#pragma unroll
            for (int r = 0; r < 4; ++r) {
                const int row = m0 + wm * 64 + mi * 16 + rq + r;
                const size_t idx = (size_t)row * N + col;
                float v = acc[mi][ni][r] + bv;
                if (MODE == 0) {
                    if (col < 1024) {
                        ((_Float16*)Cout)[idx] = (_Float16)v;
                    } else {
                        // V region -> vT[(bf*8+h)][dk][s]  (64 x 1024 per head)
                        const int dkf = col - 1024;
                        const size_t tidx = (((size_t)((row >> 10) * 8 + (dkf >> 6))) << 16)
                                          + ((size_t)(dkf & 63) << 10) + (size_t)(row & 1023);
                        vTout[tidx] = (_Float16)v;
                    }
                } else if (MODE == 1) {
                    // gelu(v) ~= v * sigmoid(1.5957691*v*(1+0.044715 v^2))
                    float t2 = -1.5957691216057308f * v * fmaf(v * v, 0.044715f, 1.0f);
                    float e = __expf(t2);
                    ((_Float16*)Cout)[idx] = (_Float16)(v * __builtin_amdgcn_rcpf(1.0f + e));
                } else if (MODE == 2) {
                    ((float*)Cout)[idx] = v + resf[idx];
                } else {
                    ((float*)Cout)[idx] = v + (float)resh[idx];
                }
            }
        }
    }
}

// ---------------- flash attention (no-max softmax, 128-query tile) ----------------
// grid: (S/128, BF*H) = (8, 256). block = 4 waves; each wave owns 32 queries.
// QKV layout [32768, 1536]: Q cols 0..511, K cols 512..1023 (V lives in vT).
// vT layout: [bf*8+h][dk=64][s=1024] f16.
//
// v5 = v4 + T14 async-STAGE split: next tile's K/V global loads are issued at the
//      TOP of the compute phase (held in regs), ds_written only after the barrier.
//      Global latency hides under QK+exp+PV instead of sitting on the critical path.
//      setprio dropped (lockstep 4-wave structure = the regime where it hurts).
__global__ __launch_bounds__(256, 4)
void attn_fwd(const _Float16* __restrict__ QKV, const _Float16* __restrict__ vT,
              const int* __restrict__ mask, _Float16* __restrict__ ctx)
{
    constexpr int SQ = 68;                           // padded row stride (halves)
    __shared__ __align__(16) _Float16 Ks[64 * SQ];       // 8704 B
    __shared__ __align__(16) _Float16 Vts[64 * SQ];      // 8704 B
    __shared__ __align__(16) _Float16 Ps[4][32 * SQ];    // 17408 B
    __shared__ float scs[1024];                          // 4096 B -> 38912 total

    const int tid = threadIdx.x;
    const int lane = tid & 63;
    const int w = tid >> 6;

    // XCD-aware remap: blocks p with equal (p&7) land on the same XCD (round-robin
    // dispatch); give each XCD whole heads so all 8 q-tiles of a head share one L2.
    const int p = blockIdx.y * 8 + blockIdx.x;
    const int ii = p >> 3;
    const int headlin = (p & 7) * 32 + (ii >> 3);
    const int bf = headlin >> 3;
    const int hh = headlin & 7;
    const int q0 = (ii & 7) * 128;

    const int lrow = lane & 15;
    const int lq = lane >> 4;

    // fused per-key scale (softmax scale * eclipse boost) * log2(e), once
    {
        const int* mrow = mask + (bf >> 3) * 1024;   // b = bf / F
        const int i = tid * 4;
        int4 mm = *(const int4*)(mrow + i);
        scs[i + 0] = mm.x ? 0.36067376f : 0.18033688f;
        scs[i + 1] = mm.y ? 0.36067376f : 0.18033688f;
        scs[i + 2] = mm.z ? 0.36067376f : 0.18033688f;
        scs[i + 3] = mm.w ? 0.36067376f : 0.18033688f;
    }
    constexpr float B2 = -7.2134752f;                // -5 * log2(e)

    // Q fragments straight from global (once per block, amortized over 8 tiles)
    half8 qf[2][2];
#pragma unroll
    for (int qi = 0; qi < 2; ++qi) {
        const _Float16* qp = QKV + (size_t)(bf * 1024 + q0 + w * 32 + qi * 16 + lrow) * 1536 + hh * 64 + lq * 8;
        qf[qi][0] = *(const half8*)qp;
        qf[qi][1] = *(const half8*)(qp + 32);
    }

    const _Float16* Kg = QKV + (size_t)bf * 1024 * 1536 + 512 + hh * 64;
    const _Float16* Vg = vT + (size_t)(bf * 8 + hh) * 65536;

    f32x4 acc[2][4];
#pragma unroll
    for (int qi = 0; qi < 2; ++qi)
#pragma unroll
        for (int d = 0; d < 4; ++d) acc[qi][d] = (f32x4)0.0f;
    f32x4 acc_l[2] = {(f32x4)0.0f, (f32x4)0.0f};
    const half8 ones = {(_Float16)1.f,(_Float16)1.f,(_Float16)1.f,(_Float16)1.f,
                        (_Float16)1.f,(_Float16)1.f,(_Float16)1.f,(_Float16)1.f};
    _Float16* Pw = &Ps[w][0];

    // staging geometry: thread covers rows r and r+32, 16B at col c
    const int sr = tid >> 3, sc = (tid & 7) * 8;
    uint4 kr0, kr1, vr0, vr1;

    // prologue: stage tile 0
    kr0 = *(const uint4*)(Kg + (size_t)(0 + sr) * 1536 + sc);
    kr1 = *(const uint4*)(Kg + (size_t)(0 + sr + 32) * 1536 + sc);
    vr0 = *(const uint4*)(Vg + (size_t)sr * 1024 + 0 + sc);
    vr1 = *(const uint4*)(Vg + (size_t)(sr + 32) * 1024 + 0 + sc);
    *(uint4*)&Ks[sr * SQ + sc]         = kr0;
    *(uint4*)&Ks[(sr + 32) * SQ + sc]  = kr1;
    *(uint4*)&Vts[sr * SQ + sc]        = vr0;
    *(uint4*)&Vts[(sr + 32) * SQ + sc] = vr1;
    __syncthreads();

    for (int kt = 0; kt < 1024; kt += 64) {
        // issue NEXT tile's global loads now; latency hides under this tile's compute
        const int ktn = (kt + 64) & 1023;        // last iter wraps to 0 (unused)
        kr0 = *(const uint4*)(Kg + (size_t)(ktn + sr) * 1536 + sc);
        kr1 = *(const uint4*)(Kg + (size_t)(ktn + sr + 32) * 1536 + sc);
        vr0 = *(const uint4*)(Vg + (size_t)sr * 1024 + ktn + sc);
        vr1 = *(const uint4*)(Vg + (size_t)(sr + 32) * 1024 + ktn + sc);

        // QK^T -> p = exp2(s*sc2 + B2), no max tracking (|s| bounded << 88)
#pragma unroll
        for (int nt = 0; nt < 4; ++nt) {
            half8 kf0 = *(const half8*)(Ks + (nt * 16 + lrow) * SQ + lq * 8);
            half8 kf1 = *(const half8*)(Ks + (nt * 16 + lrow) * SQ + 32 + lq * 8);
            const float sc2 = scs[kt + nt * 16 + lrow];
#pragma unroll
            for (int qi = 0; qi < 2; ++qi) {
                f32x4 s = (f32x4)0.0f;
                s = __builtin_amdgcn_mfma_f32_16x16x32_f16(qf[qi][0], kf0, s, 0, 0, 0);
                s = __builtin_amdgcn_mfma_f32_16x16x32_f16(qf[qi][1], kf1, s, 0, 0, 0);
#pragma unroll
                for (int r = 0; r < 4; ++r)
                    Pw[(qi * 16 + lq * 4 + r) * SQ + nt * 16 + lrow] =
                        (_Float16)EXP2F(fmaf(s[r], sc2, B2));
            }
        }

        // P (C-layout -> A-layout via per-wave LDS), then PV
        half8 pf[2][2];
#pragma unroll
        for (int qi = 0; qi < 2; ++qi) {
            pf[qi][0] = *(const half8*)(Pw + (qi * 16 + lrow) * SQ + lq * 8);
            pf[qi][1] = *(const half8*)(Pw + (qi * 16 + lrow) * SQ + 32 + lq * 8);
        }
        half8 vf[4][2];
#pragma unroll
        for (int d = 0; d < 4; ++d) {
            vf[d][0] = *(const half8*)(Vts + (d * 16 + lrow) * SQ + lq * 8);
            vf[d][1] = *(const half8*)(Vts + (d * 16 + lrow) * SQ + 32 + lq * 8);
        }
#pragma unroll
        for (int d = 0; d < 4; ++d)
#pragma unroll
            for (int qi = 0; qi < 2; ++qi) {
                acc[qi][d] = __builtin_amdgcn_mfma_f32_16x16x32_f16(pf[qi][0], vf[d][0], acc[qi][d], 0, 0, 0);
                acc[qi][d] = __builtin_amdgcn_mfma_f32_16x16x32_f16(pf[qi][1], vf[d][1], acc[qi][d], 0, 0, 0);
            }
        // softmax denominator: row-sum of P via ones-MFMA (same C layout as acc)
#pragma unroll
        for (int qi = 0; qi < 2; ++qi) {
            acc_l[qi] = __builtin_amdgcn_mfma_f32_16x16x32_f16(pf[qi][0], ones, acc_l[qi], 0, 0, 0);
            acc_l[qi] = __builtin_amdgcn_mfma_f32_16x16x32_f16(pf[qi][1], ones, acc_l[qi], 0, 0, 0);
        }

        __syncthreads();                       // all waves done reading Ks/Vts
        // write next tile (compiler inserts the vmcnt wait on kr*/vr* here)
        *(uint4*)&Ks[sr * SQ + sc]         = kr0;
        *(uint4*)&Ks[(sr + 32) * SQ + sc]  = kr1;
        *(uint4*)&Vts[sr * SQ + sc]        = vr0;
        *(uint4*)&Vts[(sr + 32) * SQ + sc] = vr1;
        __syncthreads();                       // staged data visible
    }

#pragma unroll
    for (int qi = 0; qi < 2; ++qi) {
#pragma unroll
        for (int r = 0; r < 4; ++r) {
            const float inv = 1.0f / acc_l[qi][r];
            const int row = q0 + w * 32 + qi * 16 + lq * 4 + r;
            _Float16* cp = ctx + ((size_t)bf * 1024 + row) * 512 + hh * 64;
#pragma unroll
            for (int d = 0; d < 4; ++d)
                cp[d * 16 + lrow] = (_Float16)(acc[qi][d][r] * inv);
        }
    }
}

// ---------------- LayerNorm over D=512, 1 wave per row ----------------
template<int OUTH>
__global__ __launch_bounds__(256)
void ln_fused(const float* __restrict__ X, const float* __restrict__ gma,
              const float* __restrict__ bta, float* __restrict__ outF,
              _Float16* __restrict__ outH)
{
    const int row = blockIdx.x * 4 + (threadIdx.x >> 6);
    const int lane = threadIdx.x & 63;
    const float4* xr = (const float4*)(X + (size_t)row * 512);
    float4 a = xr[lane * 2], c = xr[lane * 2 + 1];
    float s  = a.x + a.y + a.z + a.w + c.x + c.y + c.z + c.w;
    float s2 = a.x * a.x + a.y * a.y + a.z * a.z + a.w * a.w
             + c.x * c.x + c.y * c.y + c.z * c.z + c.w * c.w;
#pragma unroll
    for (int m = 1; m < 64; m <<= 1) { s += __shfl_xor(s, m); s2 += __shfl_xor(s2, m); }
    const float mean = s * (1.0f / 512.0f);
    const float inv = rsqrtf(s2 * (1.0f / 512.0f) - mean * mean + 1e-5f);
    const float4* gp = (const float4*)gma;
    const float4* bp = (const float4*)bta;
    float4 g0 = gp[lane * 2], g1 = gp[lane * 2 + 1];
    float4 b0 = bp[lane * 2], b1 = bp[lane * 2 + 1];
    float4 o0, o1;
    o0.x = (a.x - mean) * inv * g0.x + b0.x; o0.y = (a.y - mean) * inv * g0.y + b0.y;
    o0.z = (a.z - mean) * inv * g0.z + b0.z; o0.w = (a.w - mean) * inv * g0.w + b0.w;
    o1.x = (c.x - mean) * inv * g1.x + b1.x; o1.y = (c.y - mean) * inv * g1.y + b1.y;
    o1.z = (c.z - mean) * inv * g1.z + b1.z; o1.w = (c.w - mean) * inv * g1.w + b1.w;
    if (OUTH) {
        half8 hv;
        hv[0] = (_Float16)o0.x; hv[1] = (_Float16)o0.y; hv[2] = (_Float16)o0.z; hv[3] = (_Float16)o0.w;
        hv[4] = (_Float16)o1.x; hv[5] = (_Float16)o1.y; hv[6] = (_Float16)o1.z; hv[7] = (_Float16)o1.w;
        *((half8*)(outH + (size_t)row * 512) + lane) = hv;
    } else {
        float4* op = (float4*)(outF + (size_t)row * 512);
        op[lane * 2] = o0; op[lane * 2 + 1] = o1;
    }
}

extern "C" void kernel_launch(void* const* d_in, const int* in_sizes, int n_in,
                              void* d_out, int out_size, void* d_ws, size_t ws_size,
                              hipStream_t stream)
{
    const float* x   = (const float*)d_in[0];
    const int* mask  = (const int*)d_in[1];
    const float* wq  = (const float*)d_in[2];  const float* bq  = (const float*)d_in[3];
    const float* wk  = (const float*)d_in[4];  const float* bk  = (const float*)d_in[5];
    const float* wv  = (const float*)d_in[6];  const float* bv  = (const float*)d_in[7];
    const float* wo  = (const float*)d_in[8];  const float* bo  = (const float*)d_in[9];
    const float* w1  = (const float*)d_in[10]; const float* b1  = (const float*)d_in[11];
    const float* w2  = (const float*)d_in[12]; const float* b2  = (const float*)d_in[13];
    const float* g1  = (const float*)d_in[14]; const float* be1 = (const float*)d_in[15];
    const float* g2  = (const float*)d_in[16]; const float* be2 = (const float*)d_in[17];
    float* out = (float*)d_out;

    char* ws = (char*)d_ws;
    _Float16* qkvh = (_Float16*)(ws);                 // [32768,1536] (V region unused)
    _Float16* ctxh = (_Float16*)(ws + 100663296);
    _Float16* gh   = (_Float16*)(ws);
    _Float16* xh   = (_Float16*)(ws + 134217728);
    float*    res  = (float*)   (ws + 134217728);
    _Float16* vTh  = (_Float16*)(ws + 167772160);     // [256][64][1024] f16
    _Float16* hhb  = (_Float16*)(ws + 201326592);
    float*    biasf= (float*)   (ws + 201326592);
    _Float16* qkvw = (_Float16*)(ws + 234881024);
    _Float16* woh  = (_Float16*)(ws + 236453888);
    _Float16* w1h  = (_Float16*)(ws + 236978176);
    _Float16* w2h  = (_Float16*)(ws + 239075328);

    dim3 blk(256);

    cvt_all<<<9728, blk, 0, stream>>>(x, wq, wk, wv, wo, w1, w2, xh, qkvw, woh, w1h, w2h);
    pack_bias<<<6, blk, 0, stream>>>(bq, bk, bv, biasf);

    // fused QKV: [32768,512] @ [1536,512]^T -> Q/K into qkvh, V transposed into vTh
    gemm_bt<0><<<dim3(12, 256), blk, 0, stream>>>(xh, qkvw, biasf, nullptr, nullptr, vTh, qkvh, 32768, 1536, 512);

    // flash attention with eclipse boost (128-query tiles, async-staged K/V^T)
    attn_fwd<<<dim3(8, 256), blk, 0, stream>>>(qkvh, vTh, mask, ctxh);

    // WO projection + bias + fp32 residual (original x, raw reshape)
    gemm_bt<2><<<dim3(4, 256), blk, 0, stream>>>(ctxh, woh, bo, x, nullptr, nullptr, res, 32768, 512, 512);

    // LN1 -> h (f16)
    ln_fused<1><<<8192, blk, 0, stream>>>(res, g1, be1, nullptr, hhb);

    // FF1 + gelu: [32768,512] @ [2048,512]^T
    gemm_bt<1><<<dim3(16, 256), blk, 0, stream>>>(hhb, w1h, b1, nullptr, nullptr, nullptr, gh, 32768, 2048, 512);

    // FF2 + bias + residual(h): [32768,2048] @ [512,2048]^T
    gemm_bt<3><<<dim3(4, 256), blk, 0, stream>>>(gh, w2h, b2, nullptr, hhb, nullptr, res, 32768, 512, 2048);

    // LN2 -> out (f32)
    ln_fused<0><<<8192, blk, 0, stream>>>(res, g2, be2, out, nullptr);
}